// Round 5
// baseline (616.734 us; speedup 1.0000x reference)
//
#include <hip/hip_runtime.h>
#include <hip/hip_bf16.h>
#include <cstddef>
#include <cstdint>

#define N_NODES 50000
#define N_EDGES 800000
#define IN_CH 128
#define HID 64
#define OUT_CH 32

#define SCAN_B 196   // ceil(50000/256)
#define NBUCK 196    // buckets of 256 dst nodes
#define BCAP 8192    // LDS bucket capacity (mean 4082, sigma ~64)

// bf16 round-to-nearest-even, bit form
__device__ __forceinline__ unsigned short bf16rne(float f) {
    union { float f; unsigned u; } c; c.f = f;
    unsigned r = c.u + 0x7FFF + ((c.u >> 16) & 1);
    return (unsigned short)(r >> 16);
}
__device__ __forceinline__ float bf16f(unsigned short b) {
    union { unsigned u; float f; } c; c.u = ((unsigned)b) << 16;
    return c.f;
}

// ---------------- edge decode (int32 vs int64 decided at runtime) ----------
__device__ __forceinline__ void load_edge(const void* ei, int flag, int e, int& s, int& d) {
    if (flag) {  // int64 data
        const long long* p = (const long long*)ei;
        s = (int)p[e];
        d = (int)p[e + N_EDGES];
    } else {     // int32 data
        const int* p = (const int*)ei;
        s = p[e];
        d = p[e + N_EDGES];
    }
}

// flag=1 iff data is int64: odd int32 words (high halves) are all zero.
__global__ __launch_bounds__(256) void detect_kernel(const unsigned* ei, int* flagp) {
    __shared__ unsigned red[256];
    unsigned acc = 0;
    for (int i = threadIdx.x; i < 2048; i += 256) acc |= ei[2 * i + 1];
    red[threadIdx.x] = acc;
    __syncthreads();
    if (threadIdx.x == 0) {
        unsigned o = 0;
        for (int i = 0; i < 256; ++i) o |= red[i];
        *flagp = (o == 0) ? 1 : 0;
    }
}

__global__ __launch_bounds__(256) void deg_kernel(const void* ei, const int* flagp, int* deg) {
    const int flag = *flagp;
    int e = blockIdx.x * 256 + threadIdx.x;
    if (e < N_EDGES) {
        int s, d;
        load_edge(ei, flag, e, s, d);
        atomicAdd(&deg[d], 1);
    }
}

__global__ __launch_bounds__(256) void dis_kernel(const int* deg, float* dis) {
    int i = blockIdx.x * 256 + threadIdx.x;
    if (i < N_NODES) dis[i] = rsqrtf((float)deg[i] + 1.0f);
}

// ---- scan phase 1: per-block sums of deg (256 elems/block) ----------------
__global__ __launch_bounds__(256) void scan1_kernel(const int* __restrict__ deg,
                                                    int* __restrict__ bsum) {
    __shared__ int sm[256];
    int i = blockIdx.x * 256 + threadIdx.x;
    int v = (i < N_NODES) ? deg[i] : 0;
    sm[threadIdx.x] = v;
    __syncthreads();
#pragma unroll
    for (int off = 128; off > 0; off >>= 1) {
        if (threadIdx.x < off) sm[threadIdx.x] += sm[threadIdx.x + off];
        __syncthreads();
    }
    if (threadIdx.x == 0) bsum[blockIdx.x] = sm[0];
}

// ---- scan phase 2: exclusive scan of the 196 block sums (1 tiny block) ----
__global__ __launch_bounds__(256) void scan2_kernel(const int* __restrict__ bsum,
                                                    int* __restrict__ ebsum) {
    __shared__ int sm[256];
    int t = threadIdx.x;
    int v = (t < SCAN_B) ? bsum[t] : 0;
    sm[t] = v;
    __syncthreads();
#pragma unroll
    for (int off = 1; off < 256; off <<= 1) {
        int u = (t >= off) ? sm[t - off] : 0;
        __syncthreads();
        sm[t] += u;
        __syncthreads();
    }
    if (t < SCAN_B) ebsum[t] = sm[t] - v;  // exclusive
}

// ---- scan phase 3: intra-block exclusive scan + offset -> rowptr, cursor --
__global__ __launch_bounds__(256) void scan3_kernel(const int* __restrict__ deg,
                                                    const int* __restrict__ ebsum,
                                                    int* __restrict__ rowptr,
                                                    int* __restrict__ cursor) {
    __shared__ int sm[256];
    const int t = threadIdx.x;
    const int i = blockIdx.x * 256 + t;
    int v = (i < N_NODES) ? deg[i] : 0;
    sm[t] = v;
    __syncthreads();
#pragma unroll
    for (int off = 1; off < 256; off <<= 1) {
        int u = (t >= off) ? sm[t - off] : 0;
        __syncthreads();
        sm[t] += u;
        __syncthreads();
    }
    int incl = sm[t];
    int base = ebsum[blockIdx.x];
    if (i < N_NODES) {
        int excl = base + incl - v;
        rowptr[i] = excl;
        cursor[i] = excl;
        if (i == N_NODES - 1) rowptr[N_NODES] = base + incl;
    }
}

// ---- bucket cursors: bcur[b] = rowptr[b*256] ------------------------------
__global__ __launch_bounds__(256) void bcur_init_kernel(const int* __restrict__ rowptr,
                                                        int* __restrict__ bcur) {
    int t = threadIdx.x;
    if (t < NBUCK) bcur[t] = rowptr[t << 8];
}

// ---- phase A: partition edges into dst-buckets; pack src|dlocal in u32 ----
__global__ __launch_bounds__(256) void partition_kernel(const void* ei, const int* flagp,
                                                        int* __restrict__ bcur,
                                                        unsigned* __restrict__ packed) {
    const int flag = *flagp;
    int e = blockIdx.x * 256 + threadIdx.x;
    if (e < N_EDGES) {
        int s, d;
        load_edge(ei, flag, e, s, d);
        int b = d >> 8;
        int pos = atomicAdd(&bcur[b], 1);
        packed[pos] = (unsigned)s | ((unsigned)(d & 255) << 16);
    }
}

// ---- phase B: per-bucket LDS counting sort -> coalesced sortedsrc ---------
__global__ __launch_bounds__(256) void bucket_kernel(const int* __restrict__ rowptr,
                                                     const unsigned* __restrict__ packed,
                                                     int* __restrict__ cursor,
                                                     int* __restrict__ sortedsrc) {
    __shared__ int lcur[256];
    __shared__ int lbuf[BCAP];
    const int b = blockIdx.x;
    const int nodebase = b << 8;
    const int rbase = rowptr[nodebase];
    const int rend = rowptr[min(nodebase + 256, N_NODES)];
    const int bsize = rend - rbase;
    const int t = threadIdx.x;

    if (bsize <= BCAP) {
        const int nb = min(256, N_NODES - nodebase);
        lcur[t] = (t < nb) ? (rowptr[nodebase + t] - rbase) : bsize;
        __syncthreads();
        for (int i = t; i < bsize; i += 256) {
            unsigned p = packed[rbase + i];
            int dl = (int)(p >> 16);
            int s = (int)(p & 0xFFFFu);
            int pos = atomicAdd(&lcur[dl], 1);
            lbuf[pos] = s;
        }
        __syncthreads();
        for (int i = t; i < bsize; i += 256)
            sortedsrc[rbase + i] = lbuf[i];
    } else {
        // fallback (can only trigger on pathological degree skew)
        for (int i = t; i < bsize; i += 256) {
            unsigned p = packed[rbase + i];
            int dl = (int)(p >> 16);
            int s = (int)(p & 0xFFFFu);
            int pos = atomicAdd(&cursor[nodebase + dl], 1);
            sortedsrc[pos] = s;
        }
    }
}

// --------------- GEMM1: h1b = bf16(x @ W1) -----------------
__global__ __launch_bounds__(256) void gemm1_kernel(
        const float* __restrict__ x, const float* __restrict__ W1,
        unsigned short* __restrict__ h1b) {
    extern __shared__ float smem[];
    float (*xs)[132] = (float(*)[132])smem;             // 64 x 132
    float (*wsh)[68] = (float(*)[68])(smem + 64 * 132); // 128 x 68

    const int t = threadIdx.x;
    const int brow = blockIdx.x * 64;

    for (int f = t; f < 2048; f += 256) {
        int r = f >> 4, c = (f & 15) << 2;
        float4 v = ((const float4*)W1)[f];
        *(float4*)&wsh[r][c] = v;
    }
    for (int f = t; f < 2048; f += 256) {
        int r = f >> 5, c = (f & 31) << 2;
        int gr = brow + r;
        float4 v = make_float4(0.f, 0.f, 0.f, 0.f);
        if (gr < N_NODES) v = *(const float4*)(x + gr * IN_CH + c);
        *(float4*)&xs[r][c] = v;
    }
    __syncthreads();

    const int tc = (t & 15) << 2;
    const int tr = (t >> 4) << 2;
    float acc[4][4] = {};
#pragma unroll 4
    for (int k4 = 0; k4 < 32; ++k4) {
        const int k = k4 << 2;
        float xr[4][4], wr[4][4];
#pragma unroll
        for (int i = 0; i < 4; ++i) {
            float4 v = *(const float4*)&xs[tr + i][k];
            xr[i][0] = v.x; xr[i][1] = v.y; xr[i][2] = v.z; xr[i][3] = v.w;
        }
#pragma unroll
        for (int j = 0; j < 4; ++j) {
            float4 v = *(const float4*)&wsh[k + j][tc];
            wr[j][0] = v.x; wr[j][1] = v.y; wr[j][2] = v.z; wr[j][3] = v.w;
        }
#pragma unroll
        for (int i = 0; i < 4; ++i)
#pragma unroll
            for (int c = 0; c < 4; ++c)
                acc[i][c] += xr[i][0] * wr[0][c] + xr[i][1] * wr[1][c]
                           + xr[i][2] * wr[2][c] + xr[i][3] * wr[3][c];
    }

#pragma unroll
    for (int i = 0; i < 4; ++i) {
        int r = brow + tr + i;
        if (r < N_NODES) {
            ushort4 pk;
            pk.x = bf16rne(acc[i][0]); pk.y = bf16rne(acc[i][1]);
            pk.z = bf16rne(acc[i][2]); pk.w = bf16rne(acc[i][3]);
            *(ushort4*)(h1b + r * HID + tc) = pk;
        }
    }
}

// ---- agg1: per dst node, wave of 64 lanes (= HID channels) ----------------
__global__ __launch_bounds__(256) void agg1_kernel(
        const int* __restrict__ rowptr, const int* __restrict__ sortedsrc,
        const float* __restrict__ dis, const unsigned short* __restrict__ h1b,
        const float* __restrict__ b1, float* __restrict__ agg1) {
    const int lane = threadIdx.x & 63;
    const int d = blockIdx.x * 4 + (threadIdx.x >> 6);
    if (d >= N_NODES) return;
    const int beg = rowptr[d], end = rowptr[d + 1];
    const float dd = dis[d];
    float a0 = 0.f, a1 = 0.f, a2 = 0.f, a3 = 0.f;
    int j = beg;
    for (; j + 3 < end; j += 4) {
        int s0 = sortedsrc[j], s1 = sortedsrc[j + 1];
        int s2 = sortedsrc[j + 2], s3 = sortedsrc[j + 3];
        float n0 = dis[s0] * dd, n1 = dis[s1] * dd;
        float n2 = dis[s2] * dd, n3 = dis[s3] * dd;
        a0 += bf16f(h1b[s0 * HID + lane]) * n0;
        a1 += bf16f(h1b[s1 * HID + lane]) * n1;
        a2 += bf16f(h1b[s2 * HID + lane]) * n2;
        a3 += bf16f(h1b[s3 * HID + lane]) * n3;
    }
    for (; j < end; ++j) {
        int s0 = sortedsrc[j];
        a0 += bf16f(h1b[s0 * HID + lane]) * (dis[s0] * dd);
    }
    float v = (a0 + a1) + (a2 + a3) + bf16f(h1b[d * HID + lane]) * (dd * dd) + b1[lane];
    agg1[d * HID + lane] = fmaxf(v, 0.f);
}

// --------------- GEMM2: h2b = bf16(agg1 @ W2) ------------------------------
__global__ __launch_bounds__(256) void gemm2_kernel(
        const float* __restrict__ agg1, const float* __restrict__ W2,
        unsigned short* __restrict__ h2b) {
    extern __shared__ float smem[];
    float (*xs)[68] = (float(*)[68])smem;               // 128 x 68
    float (*wsh)[36] = (float(*)[36])(smem + 128 * 68); // 64 x 36

    const int t = threadIdx.x;
    const int brow = blockIdx.x * 128;

    for (int f = t; f < 512; f += 256) {
        int r = f >> 3, c = (f & 7) << 2;
        float4 v = ((const float4*)W2)[f];
        *(float4*)&wsh[r][c] = v;
    }
    for (int f = t; f < 2048; f += 256) {
        int r = f >> 4, c = (f & 15) << 2;
        int gr = brow + r;
        float4 v = make_float4(0.f, 0.f, 0.f, 0.f);
        if (gr < N_NODES) v = *(const float4*)(agg1 + gr * HID + c);
        *(float4*)&xs[r][c] = v;
    }
    __syncthreads();

    const int tc = (t & 7) << 2;
    const int tr = (t >> 3) << 2;
    float acc[4][4] = {};
#pragma unroll 4
    for (int k4 = 0; k4 < 16; ++k4) {
        const int k = k4 << 2;
        float xr[4][4], wr[4][4];
#pragma unroll
        for (int i = 0; i < 4; ++i) {
            float4 v = *(const float4*)&xs[tr + i][k];
            xr[i][0] = v.x; xr[i][1] = v.y; xr[i][2] = v.z; xr[i][3] = v.w;
        }
#pragma unroll
        for (int j = 0; j < 4; ++j) {
            float4 v = *(const float4*)&wsh[k + j][tc];
            wr[j][0] = v.x; wr[j][1] = v.y; wr[j][2] = v.z; wr[j][3] = v.w;
        }
#pragma unroll
        for (int i = 0; i < 4; ++i)
#pragma unroll
            for (int c = 0; c < 4; ++c)
                acc[i][c] += xr[i][0] * wr[0][c] + xr[i][1] * wr[1][c]
                           + xr[i][2] * wr[2][c] + xr[i][3] * wr[3][c];
    }

#pragma unroll
    for (int i = 0; i < 4; ++i) {
        int r = brow + tr + i;
        if (r < N_NODES) {
            ushort4 pk;
            pk.x = bf16rne(acc[i][0]); pk.y = bf16rne(acc[i][1]);
            pk.z = bf16rne(acc[i][2]); pk.w = bf16rne(acc[i][3]);
            *(ushort4*)(h2b + r * OUT_CH + tc) = pk;
        }
    }
}

// ---- agg2: per dst node, one wave; halves handle interleaved edges --------
__global__ __launch_bounds__(256) void agg2_kernel(
        const int* __restrict__ rowptr, const int* __restrict__ sortedsrc,
        const float* __restrict__ dis, const unsigned short* __restrict__ h2b,
        const float* __restrict__ b2, float* __restrict__ out) {
    const int lane = threadIdx.x & 63;
    const int c = lane & 31;
    const int half = lane >> 5;
    const int d = blockIdx.x * 4 + (threadIdx.x >> 6);
    if (d >= N_NODES) return;
    const int beg = rowptr[d], end = rowptr[d + 1];
    const float dd = dis[d];
    float a0 = 0.f, a1 = 0.f;
    int j = beg + half;
    for (; j + 2 < end; j += 4) {
        int s0 = sortedsrc[j], s1 = sortedsrc[j + 2];
        a0 += bf16f(h2b[s0 * OUT_CH + c]) * (dis[s0] * dd);
        a1 += bf16f(h2b[s1 * OUT_CH + c]) * (dis[s1] * dd);
    }
    if (j < end) {
        int s0 = sortedsrc[j];
        a0 += bf16f(h2b[s0 * OUT_CH + c]) * (dis[s0] * dd);
    }
    float acc = a0 + a1;
    acc += __shfl_xor(acc, 32, 64);
    if (half == 0) {
        float v = acc + bf16f(h2b[d * OUT_CH + c]) * (dd * dd) + b2[c];
        out[d * OUT_CH + c] = v;
    }
}

extern "C" void kernel_launch(void* const* d_in, const int* in_sizes, int n_in,
                              void* d_out, int out_size, void* d_ws, size_t ws_size,
                              hipStream_t stream) {
    const float* x  = (const float*)d_in[0];
    const float* W1 = (const float*)d_in[1];
    const float* b1 = (const float*)d_in[2];
    const float* W2 = (const float*)d_in[3];
    const float* b2 = (const float*)d_in[4];
    const void*  ei = d_in[5];
    float* out = (float*)d_out;

    char* ws = (char*)d_ws;
    int*   flagp     = (int*)ws;                          // 512 B
    int*   deg       = (int*)(ws + 512);                  // 200704 B
    float* dis       = (float*)(ws + 512 + 200704);       // 200704 B
    int*   rowptr    = (int*)(ws + 512 + 2 * 200704);     // 200704 B (50001 used)
    int*   cursor    = (int*)(ws + 512 + 3 * 200704);     // 200704 B
    int*   bsum      = (int*)(ws + 512 + 4 * 200704);     // 1024 B
    int*   ebsum     = bsum + 256;                        // 1024 B
    int*   bcur      = ebsum + 256;                       // 1024 B
    int*   sortedsrc = (int*)(ws + 512 + 4 * 200704 + 8192);              // 3.2 MB
    unsigned* packed = (unsigned*)((char*)sortedsrc + 3200000);           // 3.2 MB
    unsigned short* h1b = (unsigned short*)((char*)packed + 3200000);     // 6.4 MB
    float* agg1      = (float*)((char*)h1b + (size_t)N_NODES * HID * 2);  // 12.8 MB
    unsigned short* h2b = (unsigned short*)((char*)agg1 + (size_t)N_NODES * HID * 4); // 3.2 MB

    hipMemsetAsync(deg, 0, N_NODES * sizeof(int), stream);
    detect_kernel<<<1, 256, 0, stream>>>((const unsigned*)ei, flagp);
    deg_kernel<<<(N_EDGES + 255) / 256, 256, 0, stream>>>(ei, flagp, deg);
    dis_kernel<<<(N_NODES + 255) / 256, 256, 0, stream>>>(deg, dis);
    scan1_kernel<<<SCAN_B, 256, 0, stream>>>(deg, bsum);
    scan2_kernel<<<1, 256, 0, stream>>>(bsum, ebsum);
    scan3_kernel<<<SCAN_B, 256, 0, stream>>>(deg, ebsum, rowptr, cursor);
    bcur_init_kernel<<<1, 256, 0, stream>>>(rowptr, bcur);
    partition_kernel<<<(N_EDGES + 255) / 256, 256, 0, stream>>>(ei, flagp, bcur, packed);
    bucket_kernel<<<NBUCK, 256, 0, stream>>>(rowptr, packed, cursor, sortedsrc);

    size_t sh1 = (64 * 132 + 128 * 68) * sizeof(float);
    gemm1_kernel<<<(N_NODES + 63) / 64, 256, sh1, stream>>>(x, W1, h1b);

    agg1_kernel<<<(N_NODES + 3) / 4, 256, 0, stream>>>(rowptr, sortedsrc, dis, h1b, b1, agg1);

    size_t sh2 = (128 * 68 + 64 * 36) * sizeof(float);
    gemm2_kernel<<<(N_NODES + 127) / 128, 256, sh2, stream>>>(agg1, W2, h2b);

    agg2_kernel<<<(N_NODES + 3) / 4, 256, 0, stream>>>(rowptr, sortedsrc, dis, h2b, b2, out);
}

// Round 6
// 180.719 us; speedup vs baseline: 3.4127x; 3.4127x over previous
//
#include <hip/hip_runtime.h>
#include <hip/hip_bf16.h>
#include <cstddef>
#include <cstdint>

#define N_NODES 50000
#define N_EDGES 800000
#define IN_CH 128
#define HID 64
#define OUT_CH 32

#define SCAN_B 196   // ceil(50000/256)
#define NBUCK 196    // buckets of 256 dst nodes
#define BCAP 8192    // LDS bucket capacity (mean 4082, sigma ~64)
#define NBLK 256     // partition blocks
#define EPB 3125     // edges per partition block (256*3125 = 800000 exactly)

// bf16 round-to-nearest-even, bit form
__device__ __forceinline__ unsigned short bf16rne(float f) {
    union { float f; unsigned u; } c; c.f = f;
    unsigned r = c.u + 0x7FFF + ((c.u >> 16) & 1);
    return (unsigned short)(r >> 16);
}
__device__ __forceinline__ float bf16f(unsigned short b) {
    union { unsigned u; float f; } c; c.u = ((unsigned)b) << 16;
    return c.f;
}

// ---------------- edge decode (int32 vs int64 decided at runtime) ----------
__device__ __forceinline__ void load_edge(const void* ei, int flag, int e, int& s, int& d) {
    if (flag) {  // int64 data
        const long long* p = (const long long*)ei;
        s = (int)p[e];
        d = (int)p[e + N_EDGES];
    } else {     // int32 data
        const int* p = (const int*)ei;
        s = p[e];
        d = p[e + N_EDGES];
    }
}

// flag=1 iff data is int64: odd int32 words (high halves) are all zero.
__global__ __launch_bounds__(256) void detect_kernel(const unsigned* ei, int* flagp) {
    __shared__ unsigned red[256];
    unsigned acc = 0;
    for (int i = threadIdx.x; i < 2048; i += 256) acc |= ei[2 * i + 1];
    red[threadIdx.x] = acc;
    __syncthreads();
    if (threadIdx.x == 0) {
        unsigned o = 0;
        for (int i = 0; i < 256; ++i) o |= red[i];
        *flagp = (o == 0) ? 1 : 0;
    }
}

__global__ __launch_bounds__(256) void deg_kernel(const void* ei, const int* flagp, int* deg) {
    const int flag = *flagp;
    int e = blockIdx.x * 256 + threadIdx.x;
    if (e < N_EDGES) {
        int s, d;
        load_edge(ei, flag, e, s, d);
        atomicAdd(&deg[d], 1);
    }
}

__global__ __launch_bounds__(256) void dis_kernel(const int* deg, float* dis) {
    int i = blockIdx.x * 256 + threadIdx.x;
    if (i < N_NODES) dis[i] = rsqrtf((float)deg[i] + 1.0f);
}

// ---- scan phase 1: per-block sums of deg (256 elems/block) ----------------
__global__ __launch_bounds__(256) void scan1_kernel(const int* __restrict__ deg,
                                                    int* __restrict__ bsum) {
    __shared__ int sm[256];
    int i = blockIdx.x * 256 + threadIdx.x;
    int v = (i < N_NODES) ? deg[i] : 0;
    sm[threadIdx.x] = v;
    __syncthreads();
#pragma unroll
    for (int off = 128; off > 0; off >>= 1) {
        if (threadIdx.x < off) sm[threadIdx.x] += sm[threadIdx.x + off];
        __syncthreads();
    }
    if (threadIdx.x == 0) bsum[blockIdx.x] = sm[0];
}

// ---- scan phase 2: exclusive scan of the 196 block sums (1 tiny block) ----
__global__ __launch_bounds__(256) void scan2_kernel(const int* __restrict__ bsum,
                                                    int* __restrict__ ebsum) {
    __shared__ int sm[256];
    int t = threadIdx.x;
    int v = (t < SCAN_B) ? bsum[t] : 0;
    sm[t] = v;
    __syncthreads();
#pragma unroll
    for (int off = 1; off < 256; off <<= 1) {
        int u = (t >= off) ? sm[t - off] : 0;
        __syncthreads();
        sm[t] += u;
        __syncthreads();
    }
    if (t < SCAN_B) ebsum[t] = sm[t] - v;  // exclusive
}

// ---- scan phase 3: intra-block exclusive scan + offset -> rowptr, cursor --
__global__ __launch_bounds__(256) void scan3_kernel(const int* __restrict__ deg,
                                                    const int* __restrict__ ebsum,
                                                    int* __restrict__ rowptr,
                                                    int* __restrict__ cursor) {
    __shared__ int sm[256];
    const int t = threadIdx.x;
    const int i = blockIdx.x * 256 + t;
    int v = (i < N_NODES) ? deg[i] : 0;
    sm[t] = v;
    __syncthreads();
#pragma unroll
    for (int off = 1; off < 256; off <<= 1) {
        int u = (t >= off) ? sm[t - off] : 0;
        __syncthreads();
        sm[t] += u;
        __syncthreads();
    }
    int incl = sm[t];
    int base = ebsum[blockIdx.x];
    if (i < N_NODES) {
        int excl = base + incl - v;
        rowptr[i] = excl;
        cursor[i] = excl;
        if (i == N_NODES - 1) rowptr[N_NODES] = base + incl;
    }
}

// ---- partition pass A: per-block bucket histogram (no global atomics) -----
__global__ __launch_bounds__(256) void hist_kernel(const void* ei, const int* flagp,
                                                   int* __restrict__ ghist) {
    __shared__ int h[NBUCK];
    const int flag = *flagp;
    const int t = threadIdx.x;
    if (t < NBUCK) h[t] = 0;
    __syncthreads();
    const int base = blockIdx.x * EPB;
    for (int i = t; i < EPB; i += 256) {
        int s, d;
        load_edge(ei, flag, base + i, s, d);
        atomicAdd(&h[d >> 8], 1);
    }
    __syncthreads();
    if (t < NBUCK) ghist[blockIdx.x * NBUCK + t] = h[t];
}

// ---- partition pass B: per-bucket scan over the 256 block counts ----------
// one block per bucket; thread t = partition-block index.
__global__ __launch_bounds__(256) void offs_kernel(const int* __restrict__ rowptr,
                                                   const int* __restrict__ ghist,
                                                   int* __restrict__ goff) {
    __shared__ int sm[256];
    const int b = blockIdx.x;
    const int t = threadIdx.x;
    int v = ghist[t * NBUCK + b];
    sm[t] = v;
    __syncthreads();
#pragma unroll
    for (int off = 1; off < 256; off <<= 1) {
        int u = (t >= off) ? sm[t - off] : 0;
        __syncthreads();
        sm[t] += u;
        __syncthreads();
    }
    goff[t * NBUCK + b] = rowptr[b << 8] + sm[t] - v;  // exclusive prefix
}

// ---- partition pass C: scatter into disjoint per-(block,bucket) ranges ----
__global__ __launch_bounds__(256) void scatter_kernel(const void* ei, const int* flagp,
                                                      const int* __restrict__ goff,
                                                      unsigned* __restrict__ packed) {
    __shared__ int lcur[NBUCK];
    const int flag = *flagp;
    const int t = threadIdx.x;
    if (t < NBUCK) lcur[t] = goff[blockIdx.x * NBUCK + t];
    __syncthreads();
    const int base = blockIdx.x * EPB;
    for (int i = t; i < EPB; i += 256) {
        int s, d;
        load_edge(ei, flag, base + i, s, d);
        int b = d >> 8;
        int pos = atomicAdd(&lcur[b], 1);
        packed[pos] = (unsigned)s | ((unsigned)(d & 255) << 16);
    }
}

// ---- phase B: per-bucket LDS counting sort -> coalesced sortedsrc ---------
__global__ __launch_bounds__(256) void bucket_kernel(const int* __restrict__ rowptr,
                                                     const unsigned* __restrict__ packed,
                                                     int* __restrict__ cursor,
                                                     int* __restrict__ sortedsrc) {
    __shared__ int lcur[256];
    __shared__ int lbuf[BCAP];
    const int b = blockIdx.x;
    const int nodebase = b << 8;
    const int rbase = rowptr[nodebase];
    const int rend = rowptr[min(nodebase + 256, N_NODES)];
    const int bsize = rend - rbase;
    const int t = threadIdx.x;

    if (bsize <= BCAP) {
        const int nb = min(256, N_NODES - nodebase);
        lcur[t] = (t < nb) ? (rowptr[nodebase + t] - rbase) : bsize;
        __syncthreads();
        for (int i = t; i < bsize; i += 256) {
            unsigned p = packed[rbase + i];
            int dl = (int)(p >> 16);
            int s = (int)(p & 0xFFFFu);
            int pos = atomicAdd(&lcur[dl], 1);
            lbuf[pos] = s;
        }
        __syncthreads();
        for (int i = t; i < bsize; i += 256)
            sortedsrc[rbase + i] = lbuf[i];
    } else {
        // fallback (can only trigger on pathological degree skew)
        for (int i = t; i < bsize; i += 256) {
            unsigned p = packed[rbase + i];
            int dl = (int)(p >> 16);
            int s = (int)(p & 0xFFFFu);
            int pos = atomicAdd(&cursor[nodebase + dl], 1);
            sortedsrc[pos] = s;
        }
    }
}

// --------------- GEMM1: h1b = bf16(x @ W1) -----------------
__global__ __launch_bounds__(256) void gemm1_kernel(
        const float* __restrict__ x, const float* __restrict__ W1,
        unsigned short* __restrict__ h1b) {
    extern __shared__ float smem[];
    float (*xs)[132] = (float(*)[132])smem;             // 64 x 132
    float (*wsh)[68] = (float(*)[68])(smem + 64 * 132); // 128 x 68

    const int t = threadIdx.x;
    const int brow = blockIdx.x * 64;

    for (int f = t; f < 2048; f += 256) {
        int r = f >> 4, c = (f & 15) << 2;
        float4 v = ((const float4*)W1)[f];
        *(float4*)&wsh[r][c] = v;
    }
    for (int f = t; f < 2048; f += 256) {
        int r = f >> 5, c = (f & 31) << 2;
        int gr = brow + r;
        float4 v = make_float4(0.f, 0.f, 0.f, 0.f);
        if (gr < N_NODES) v = *(const float4*)(x + gr * IN_CH + c);
        *(float4*)&xs[r][c] = v;
    }
    __syncthreads();

    const int tc = (t & 15) << 2;
    const int tr = (t >> 4) << 2;
    float acc[4][4] = {};
#pragma unroll 4
    for (int k4 = 0; k4 < 32; ++k4) {
        const int k = k4 << 2;
        float xr[4][4], wr[4][4];
#pragma unroll
        for (int i = 0; i < 4; ++i) {
            float4 v = *(const float4*)&xs[tr + i][k];
            xr[i][0] = v.x; xr[i][1] = v.y; xr[i][2] = v.z; xr[i][3] = v.w;
        }
#pragma unroll
        for (int j = 0; j < 4; ++j) {
            float4 v = *(const float4*)&wsh[k + j][tc];
            wr[j][0] = v.x; wr[j][1] = v.y; wr[j][2] = v.z; wr[j][3] = v.w;
        }
#pragma unroll
        for (int i = 0; i < 4; ++i)
#pragma unroll
            for (int c = 0; c < 4; ++c)
                acc[i][c] += xr[i][0] * wr[0][c] + xr[i][1] * wr[1][c]
                           + xr[i][2] * wr[2][c] + xr[i][3] * wr[3][c];
    }

#pragma unroll
    for (int i = 0; i < 4; ++i) {
        int r = brow + tr + i;
        if (r < N_NODES) {
            ushort4 pk;
            pk.x = bf16rne(acc[i][0]); pk.y = bf16rne(acc[i][1]);
            pk.z = bf16rne(acc[i][2]); pk.w = bf16rne(acc[i][3]);
            *(ushort4*)(h1b + r * HID + tc) = pk;
        }
    }
}

// ---- agg1: per dst node, wave of 64 lanes (= HID channels) ----------------
__global__ __launch_bounds__(256) void agg1_kernel(
        const int* __restrict__ rowptr, const int* __restrict__ sortedsrc,
        const float* __restrict__ dis, const unsigned short* __restrict__ h1b,
        const float* __restrict__ b1, float* __restrict__ agg1) {
    const int lane = threadIdx.x & 63;
    const int d = blockIdx.x * 4 + (threadIdx.x >> 6);
    if (d >= N_NODES) return;
    const int beg = rowptr[d], end = rowptr[d + 1];
    const float dd = dis[d];
    float a0 = 0.f, a1 = 0.f, a2 = 0.f, a3 = 0.f;
    int j = beg;
    for (; j + 3 < end; j += 4) {
        int s0 = sortedsrc[j], s1 = sortedsrc[j + 1];
        int s2 = sortedsrc[j + 2], s3 = sortedsrc[j + 3];
        float n0 = dis[s0] * dd, n1 = dis[s1] * dd;
        float n2 = dis[s2] * dd, n3 = dis[s3] * dd;
        a0 += bf16f(h1b[s0 * HID + lane]) * n0;
        a1 += bf16f(h1b[s1 * HID + lane]) * n1;
        a2 += bf16f(h1b[s2 * HID + lane]) * n2;
        a3 += bf16f(h1b[s3 * HID + lane]) * n3;
    }
    for (; j < end; ++j) {
        int s0 = sortedsrc[j];
        a0 += bf16f(h1b[s0 * HID + lane]) * (dis[s0] * dd);
    }
    float v = (a0 + a1) + (a2 + a3) + bf16f(h1b[d * HID + lane]) * (dd * dd) + b1[lane];
    agg1[d * HID + lane] = fmaxf(v, 0.f);
}

// --------------- GEMM2: h2b = bf16(agg1 @ W2) ------------------------------
__global__ __launch_bounds__(256) void gemm2_kernel(
        const float* __restrict__ agg1, const float* __restrict__ W2,
        unsigned short* __restrict__ h2b) {
    extern __shared__ float smem[];
    float (*xs)[68] = (float(*)[68])smem;               // 128 x 68
    float (*wsh)[36] = (float(*)[36])(smem + 128 * 68); // 64 x 36

    const int t = threadIdx.x;
    const int brow = blockIdx.x * 128;

    for (int f = t; f < 512; f += 256) {
        int r = f >> 3, c = (f & 7) << 2;
        float4 v = ((const float4*)W2)[f];
        *(float4*)&wsh[r][c] = v;
    }
    for (int f = t; f < 2048; f += 256) {
        int r = f >> 4, c = (f & 15) << 2;
        int gr = brow + r;
        float4 v = make_float4(0.f, 0.f, 0.f, 0.f);
        if (gr < N_NODES) v = *(const float4*)(agg1 + gr * HID + c);
        *(float4*)&xs[r][c] = v;
    }
    __syncthreads();

    const int tc = (t & 7) << 2;
    const int tr = (t >> 3) << 2;
    float acc[4][4] = {};
#pragma unroll 4
    for (int k4 = 0; k4 < 16; ++k4) {
        const int k = k4 << 2;
        float xr[4][4], wr[4][4];
#pragma unroll
        for (int i = 0; i < 4; ++i) {
            float4 v = *(const float4*)&xs[tr + i][k];
            xr[i][0] = v.x; xr[i][1] = v.y; xr[i][2] = v.z; xr[i][3] = v.w;
        }
#pragma unroll
        for (int j = 0; j < 4; ++j) {
            float4 v = *(const float4*)&wsh[k + j][tc];
            wr[j][0] = v.x; wr[j][1] = v.y; wr[j][2] = v.z; wr[j][3] = v.w;
        }
#pragma unroll
        for (int i = 0; i < 4; ++i)
#pragma unroll
            for (int c = 0; c < 4; ++c)
                acc[i][c] += xr[i][0] * wr[0][c] + xr[i][1] * wr[1][c]
                           + xr[i][2] * wr[2][c] + xr[i][3] * wr[3][c];
    }

#pragma unroll
    for (int i = 0; i < 4; ++i) {
        int r = brow + tr + i;
        if (r < N_NODES) {
            ushort4 pk;
            pk.x = bf16rne(acc[i][0]); pk.y = bf16rne(acc[i][1]);
            pk.z = bf16rne(acc[i][2]); pk.w = bf16rne(acc[i][3]);
            *(ushort4*)(h2b + r * OUT_CH + tc) = pk;
        }
    }
}

// ---- agg2: per dst node, one wave; halves handle interleaved edges --------
__global__ __launch_bounds__(256) void agg2_kernel(
        const int* __restrict__ rowptr, const int* __restrict__ sortedsrc,
        const float* __restrict__ dis, const unsigned short* __restrict__ h2b,
        const float* __restrict__ b2, float* __restrict__ out) {
    const int lane = threadIdx.x & 63;
    const int c = lane & 31;
    const int half = lane >> 5;
    const int d = blockIdx.x * 4 + (threadIdx.x >> 6);
    if (d >= N_NODES) return;
    const int beg = rowptr[d], end = rowptr[d + 1];
    const float dd = dis[d];
    float a0 = 0.f, a1 = 0.f;
    int j = beg + half;
    for (; j + 2 < end; j += 4) {
        int s0 = sortedsrc[j], s1 = sortedsrc[j + 2];
        a0 += bf16f(h2b[s0 * OUT_CH + c]) * (dis[s0] * dd);
        a1 += bf16f(h2b[s1 * OUT_CH + c]) * (dis[s1] * dd);
    }
    if (j < end) {
        int s0 = sortedsrc[j];
        a0 += bf16f(h2b[s0 * OUT_CH + c]) * (dis[s0] * dd);
    }
    float acc = a0 + a1;
    acc += __shfl_xor(acc, 32, 64);
    if (half == 0) {
        float v = acc + bf16f(h2b[d * OUT_CH + c]) * (dd * dd) + b2[c];
        out[d * OUT_CH + c] = v;
    }
}

extern "C" void kernel_launch(void* const* d_in, const int* in_sizes, int n_in,
                              void* d_out, int out_size, void* d_ws, size_t ws_size,
                              hipStream_t stream) {
    const float* x  = (const float*)d_in[0];
    const float* W1 = (const float*)d_in[1];
    const float* b1 = (const float*)d_in[2];
    const float* W2 = (const float*)d_in[3];
    const float* b2 = (const float*)d_in[4];
    const void*  ei = d_in[5];
    float* out = (float*)d_out;

    char* ws = (char*)d_ws;
    int*   flagp     = (int*)ws;                          // 512 B
    int*   deg       = (int*)(ws + 512);                  // 200704 B
    float* dis       = (float*)(ws + 512 + 200704);       // 200704 B
    int*   rowptr    = (int*)(ws + 512 + 2 * 200704);     // 200704 B (50001 used)
    int*   cursor    = (int*)(ws + 512 + 3 * 200704);     // 200704 B
    int*   ghist     = (int*)(ws + 512 + 4 * 200704);     // 200704 B (256*196 used)
    int*   goff      = (int*)(ws + 512 + 5 * 200704);     // 200704 B
    int*   bsum      = (int*)(ws + 512 + 6 * 200704);     // 1024 B
    int*   ebsum     = bsum + 256;                        // 1024 B
    int*   sortedsrc = (int*)(ws + 512 + 6 * 200704 + 8192);              // 3.2 MB
    unsigned* packed = (unsigned*)((char*)sortedsrc + 3200000);           // 3.2 MB
    unsigned short* h1b = (unsigned short*)((char*)packed + 3200000);     // 6.4 MB
    float* agg1      = (float*)((char*)h1b + (size_t)N_NODES * HID * 2);  // 12.8 MB
    unsigned short* h2b = (unsigned short*)((char*)agg1 + (size_t)N_NODES * HID * 4); // 3.2 MB

    hipMemsetAsync(deg, 0, N_NODES * sizeof(int), stream);
    detect_kernel<<<1, 256, 0, stream>>>((const unsigned*)ei, flagp);
    deg_kernel<<<(N_EDGES + 255) / 256, 256, 0, stream>>>(ei, flagp, deg);
    dis_kernel<<<(N_NODES + 255) / 256, 256, 0, stream>>>(deg, dis);
    scan1_kernel<<<SCAN_B, 256, 0, stream>>>(deg, bsum);
    scan2_kernel<<<1, 256, 0, stream>>>(bsum, ebsum);
    scan3_kernel<<<SCAN_B, 256, 0, stream>>>(deg, ebsum, rowptr, cursor);

    hist_kernel<<<NBLK, 256, 0, stream>>>(ei, flagp, ghist);
    offs_kernel<<<NBUCK, 256, 0, stream>>>(rowptr, ghist, goff);
    scatter_kernel<<<NBLK, 256, 0, stream>>>(ei, flagp, goff, packed);
    bucket_kernel<<<NBUCK, 256, 0, stream>>>(rowptr, packed, cursor, sortedsrc);

    size_t sh1 = (64 * 132 + 128 * 68) * sizeof(float);
    gemm1_kernel<<<(N_NODES + 63) / 64, 256, sh1, stream>>>(x, W1, h1b);

    agg1_kernel<<<(N_NODES + 3) / 4, 256, 0, stream>>>(rowptr, sortedsrc, dis, h1b, b1, agg1);

    size_t sh2 = (128 * 68 + 64 * 36) * sizeof(float);
    gemm2_kernel<<<(N_NODES + 127) / 128, 256, sh2, stream>>>(agg1, W2, h2b);

    agg2_kernel<<<(N_NODES + 3) / 4, 256, 0, stream>>>(rowptr, sortedsrc, dis, h2b, b2, out);
}

// Round 7
// 128.405 us; speedup vs baseline: 4.8030x; 1.4074x over previous
//
#include <hip/hip_runtime.h>
#include <hip/hip_bf16.h>
#include <cstddef>
#include <cstdint>

#define N_NODES 50000
#define N_EDGES 800000
#define IN_CH 128
#define HID 64
#define OUT_CH 32

#define NBUCK 196    // buckets of 256 dst nodes
#define BCAP 8192    // LDS bucket capacity (mean 4082, sigma ~64)
#define NBLK 256     // partition blocks
#define EPB 3125     // edges per partition block (256*3125 = 800000 exactly)

typedef __attribute__((ext_vector_type(8))) short bf16x8;
typedef __attribute__((ext_vector_type(4))) float f32x4;

// bf16 round-to-nearest-even, bit form
__device__ __forceinline__ unsigned short bf16rne(float f) {
    union { float f; unsigned u; } c; c.f = f;
    unsigned r = c.u + 0x7FFF + ((c.u >> 16) & 1);
    return (unsigned short)(r >> 16);
}
__device__ __forceinline__ float bf16f(unsigned short b) {
    union { unsigned u; float f; } c; c.u = ((unsigned)b) << 16;
    return c.f;
}

// ---------------- edge decode (int32 vs int64 decided at runtime) ----------
__device__ __forceinline__ void load_edge(const void* ei, int flag, int e, int& s, int& d) {
    if (flag) {  // int64 data
        const long long* p = (const long long*)ei;
        s = (int)p[e];
        d = (int)p[e + N_EDGES];
    } else {     // int32 data
        const int* p = (const int*)ei;
        s = p[e];
        d = p[e + N_EDGES];
    }
}
__device__ __forceinline__ int load_dst(const void* ei, int flag, int e) {
    return flag ? (int)((const long long*)ei)[e + N_EDGES]
                : ((const int*)ei)[e + N_EDGES];
}

// flag=1 iff data is int64: odd int32 words (high halves) are all zero.
__global__ __launch_bounds__(256) void detect_kernel(const unsigned* ei, int* flagp) {
    __shared__ unsigned red[256];
    unsigned acc = 0;
    for (int i = threadIdx.x; i < 2048; i += 256) acc |= ei[2 * i + 1];
    red[threadIdx.x] = acc;
    __syncthreads();
    if (threadIdx.x == 0) {
        unsigned o = 0;
        for (int i = 0; i < 256; ++i) o |= red[i];
        *flagp = (o == 0) ? 1 : 0;
    }
}

// ---- pass A: per-block bucket histogram (no global atomics) ---------------
// ghistT layout: [bucket][block]
__global__ __launch_bounds__(256) void hist_kernel(const void* ei, const int* flagp,
                                                   int* __restrict__ ghistT) {
    __shared__ int h[NBUCK];
    const int flag = *flagp;
    const int t = threadIdx.x;
    if (t < NBUCK) h[t] = 0;
    __syncthreads();
    const int base = blockIdx.x * EPB;
    for (int i = t; i < EPB; i += 256)
        atomicAdd(&h[load_dst(ei, flag, base + i) >> 8], 1);
    __syncthreads();
    if (t < NBUCK) ghistT[t * NBLK + blockIdx.x] = h[t];
}

// ---- pass B1: bucket totals + exclusive scan -> bstart[0..NBUCK] ----------
__global__ __launch_bounds__(256) void btot_kernel(const int* __restrict__ ghistT,
                                                   int* __restrict__ bstart) {
    __shared__ int sm[256];
    const int t = threadIdx.x;
    int s = 0;
    if (t < NBUCK) {
        const int* row = ghistT + t * NBLK;
        for (int blk = 0; blk < NBLK; ++blk) s += row[blk];
    }
    sm[t] = s;
    __syncthreads();
    for (int off = 1; off < 256; off <<= 1) {
        int u = (t >= off) ? sm[t - off] : 0;
        __syncthreads();
        sm[t] += u;
        __syncthreads();
    }
    if (t < NBUCK) bstart[t] = sm[t] - s;
    if (t == 255) bstart[NBUCK] = sm[255];
}

// ---- pass B2: per-bucket scan over the 256 block counts -> goff[blk][b] ---
__global__ __launch_bounds__(256) void offs_kernel(const int* __restrict__ bstart,
                                                   const int* __restrict__ ghistT,
                                                   int* __restrict__ goff) {
    __shared__ int sm[256];
    const int b = blockIdx.x;
    const int t = threadIdx.x;
    int v = ghistT[b * NBLK + t];
    sm[t] = v;
    __syncthreads();
    for (int off = 1; off < 256; off <<= 1) {
        int u = (t >= off) ? sm[t - off] : 0;
        __syncthreads();
        sm[t] += u;
        __syncthreads();
    }
    goff[t * NBUCK + b] = bstart[b] + sm[t] - v;  // exclusive prefix
}

// ---- pass C: scatter into disjoint per-(block,bucket) ranges --------------
__global__ __launch_bounds__(256) void scatter_kernel(const void* ei, const int* flagp,
                                                      const int* __restrict__ goff,
                                                      unsigned* __restrict__ packed) {
    __shared__ int lcur[NBUCK];
    const int flag = *flagp;
    const int t = threadIdx.x;
    if (t < NBUCK) lcur[t] = goff[blockIdx.x * NBUCK + t];
    __syncthreads();
    const int base = blockIdx.x * EPB;
    for (int i = t; i < EPB; i += 256) {
        int s, d;
        load_edge(ei, flag, base + i, s, d);
        int b = d >> 8;
        int pos = atomicAdd(&lcur[b], 1);
        packed[pos] = (unsigned)s | ((unsigned)(d & 255) << 16);
    }
}

// ---- pass D: per-bucket LDS sort; also computes rowptr, dis ---------------
__global__ __launch_bounds__(256) void bucket_kernel(const int* __restrict__ bstart,
                                                     const unsigned* __restrict__ packed,
                                                     int* __restrict__ rowptr,
                                                     float* __restrict__ dis,
                                                     int* __restrict__ sortedsrc) {
    __shared__ int cnt[256];
    __shared__ int pref[256];
    __shared__ int lbuf[BCAP];
    const int b = blockIdx.x;
    const int nodebase = b << 8;
    const int rbase = bstart[b];
    const int bsize = bstart[b + 1] - rbase;
    const int t = threadIdx.x;
    const int nb = min(256, N_NODES - nodebase);

    cnt[t] = 0;
    __syncthreads();
    for (int i = t; i < bsize; i += 256)
        atomicAdd(&cnt[packed[rbase + i] >> 16], 1);
    __syncthreads();
    const int deg = cnt[t];
    pref[t] = deg;
    __syncthreads();
    for (int off = 1; off < 256; off <<= 1) {
        int u = (t >= off) ? pref[t - off] : 0;
        __syncthreads();
        pref[t] += u;
        __syncthreads();
    }
    const int excl = pref[t] - deg;
    if (t < nb) {
        rowptr[nodebase + t] = rbase + excl;
        dis[nodebase + t] = rsqrtf((float)deg + 1.0f);
    }
    if (b == NBUCK - 1 && t == 0) rowptr[N_NODES] = rbase + bsize;
    __syncthreads();
    cnt[t] = excl;  // reuse as cursor
    __syncthreads();
    if (bsize <= BCAP) {
        for (int i = t; i < bsize; i += 256) {
            unsigned p = packed[rbase + i];
            int pos = atomicAdd(&cnt[p >> 16], 1);
            lbuf[pos] = (int)(p & 0xFFFFu);
        }
        __syncthreads();
        for (int i = t; i < bsize; i += 256)
            sortedsrc[rbase + i] = lbuf[i];
    } else {
        // fallback: direct global scatter (pathological skew only)
        for (int i = t; i < bsize; i += 256) {
            unsigned p = packed[rbase + i];
            int pos = atomicAdd(&cnt[p >> 16], 1);
            sortedsrc[rbase + pos] = (int)(p & 0xFFFFu);
        }
    }
}

// --------------- GEMM1 (MFMA bf16): h1b = bf16(x @ W1) ---------------------
// block: 64 rows x 64 cols, K=128; 4 waves, each wave 16 rows x 64 cols.
__global__ __launch_bounds__(256) void gemm1_kernel(
        const float* __restrict__ x, const float* __restrict__ W1,
        unsigned short* __restrict__ h1b) {
    __shared__ unsigned short xa[64][136];  // x tile, bf16, +8 pad
    __shared__ unsigned short wb[64][136];  // W1 transposed [n][k], bf16
    const int t = threadIdx.x;
    const int w = t >> 6;
    const int l = t & 63;
    const int brow = blockIdx.x * 64;

    // stage x (64x128 f32 -> bf16)
    for (int f = t; f < 64 * 32; f += 256) {
        int r = f >> 5, c = (f & 31) << 2;
        int gr = brow + r;
        float4 v = (gr < N_NODES) ? *(const float4*)(x + gr * IN_CH + c)
                                  : make_float4(0.f, 0.f, 0.f, 0.f);
        xa[r][c + 0] = bf16rne(v.x); xa[r][c + 1] = bf16rne(v.y);
        xa[r][c + 2] = bf16rne(v.z); xa[r][c + 3] = bf16rne(v.w);
    }
    // stage W1 (128x64 f32) transposed -> wb[n][k] bf16
    for (int f = t; f < 128 * 16; f += 256) {
        int k = f >> 4, n = (f & 15) << 2;
        float4 v = *(const float4*)(W1 + k * HID + n);
        wb[n + 0][k] = bf16rne(v.x); wb[n + 1][k] = bf16rne(v.y);
        wb[n + 2][k] = bf16rne(v.z); wb[n + 3][k] = bf16rne(v.w);
    }
    __syncthreads();

    const int fr = l & 15;          // A row / B col within 16-tile
    const int fk = (l >> 4) << 3;   // k sub-offset (0,8,16,24)
    f32x4 acc[4] = {{0.f,0.f,0.f,0.f},{0.f,0.f,0.f,0.f},{0.f,0.f,0.f,0.f},{0.f,0.f,0.f,0.f}};
#pragma unroll
    for (int kb = 0; kb < 4; ++kb) {
        const int k = kb * 32 + fk;
        bf16x8 a = *(const bf16x8*)&xa[w * 16 + fr][k];
#pragma unroll
        for (int n = 0; n < 4; ++n) {
            bf16x8 bfr = *(const bf16x8*)&wb[n * 16 + fr][k];
            acc[n] = __builtin_amdgcn_mfma_f32_16x16x32_bf16(a, bfr, acc[n], 0, 0, 0);
        }
    }
    // C/D: col = n*16 + (l&15), row = brow + w*16 + (l>>4)*4 + i
    const int rb = brow + w * 16 + ((l >> 4) << 2);
#pragma unroll
    for (int n = 0; n < 4; ++n) {
#pragma unroll
        for (int i = 0; i < 4; ++i) {
            int r = rb + i;
            if (r < N_NODES) h1b[r * HID + n * 16 + fr] = bf16rne(acc[n][i]);
        }
    }
}

// ---- agg1: per dst node, wave of 64 lanes (= HID channels) ----------------
__global__ __launch_bounds__(256) void agg1_kernel(
        const int* __restrict__ rowptr, const int* __restrict__ sortedsrc,
        const float* __restrict__ dis, const unsigned short* __restrict__ h1b,
        const float* __restrict__ b1, float* __restrict__ agg1) {
    const int lane = threadIdx.x & 63;
    const int d = blockIdx.x * 4 + (threadIdx.x >> 6);
    if (d >= N_NODES) return;
    const int beg = rowptr[d], end = rowptr[d + 1];
    const float dd = dis[d];
    float a0 = 0.f, a1 = 0.f, a2 = 0.f, a3 = 0.f;
    int j = beg;
    for (; j + 3 < end; j += 4) {
        int s0 = sortedsrc[j], s1 = sortedsrc[j + 1];
        int s2 = sortedsrc[j + 2], s3 = sortedsrc[j + 3];
        float n0 = dis[s0] * dd, n1 = dis[s1] * dd;
        float n2 = dis[s2] * dd, n3 = dis[s3] * dd;
        a0 += bf16f(h1b[s0 * HID + lane]) * n0;
        a1 += bf16f(h1b[s1 * HID + lane]) * n1;
        a2 += bf16f(h1b[s2 * HID + lane]) * n2;
        a3 += bf16f(h1b[s3 * HID + lane]) * n3;
    }
    for (; j < end; ++j) {
        int s0 = sortedsrc[j];
        a0 += bf16f(h1b[s0 * HID + lane]) * (dis[s0] * dd);
    }
    float v = (a0 + a1) + (a2 + a3) + bf16f(h1b[d * HID + lane]) * (dd * dd) + b1[lane];
    agg1[d * HID + lane] = fmaxf(v, 0.f);
}

// --------------- GEMM2: h2b = bf16(agg1 @ W2) ------------------------------
__global__ __launch_bounds__(256) void gemm2_kernel(
        const float* __restrict__ agg1, const float* __restrict__ W2,
        unsigned short* __restrict__ h2b) {
    extern __shared__ float smem[];
    float (*xs)[68] = (float(*)[68])smem;               // 128 x 68
    float (*wsh)[36] = (float(*)[36])(smem + 128 * 68); // 64 x 36

    const int t = threadIdx.x;
    const int brow = blockIdx.x * 128;

    for (int f = t; f < 512; f += 256) {
        int r = f >> 3, c = (f & 7) << 2;
        float4 v = ((const float4*)W2)[f];
        *(float4*)&wsh[r][c] = v;
    }
    for (int f = t; f < 2048; f += 256) {
        int r = f >> 4, c = (f & 15) << 2;
        int gr = brow + r;
        float4 v = make_float4(0.f, 0.f, 0.f, 0.f);
        if (gr < N_NODES) v = *(const float4*)(agg1 + gr * HID + c);
        *(float4*)&xs[r][c] = v;
    }
    __syncthreads();

    const int tc = (t & 7) << 2;
    const int tr = (t >> 3) << 2;
    float acc[4][4] = {};
#pragma unroll 4
    for (int k4 = 0; k4 < 16; ++k4) {
        const int k = k4 << 2;
        float xr[4][4], wr[4][4];
#pragma unroll
        for (int i = 0; i < 4; ++i) {
            float4 v = *(const float4*)&xs[tr + i][k];
            xr[i][0] = v.x; xr[i][1] = v.y; xr[i][2] = v.z; xr[i][3] = v.w;
        }
#pragma unroll
        for (int j = 0; j < 4; ++j) {
            float4 v = *(const float4*)&wsh[k + j][tc];
            wr[j][0] = v.x; wr[j][1] = v.y; wr[j][2] = v.z; wr[j][3] = v.w;
        }
#pragma unroll
        for (int i = 0; i < 4; ++i)
#pragma unroll
            for (int c = 0; c < 4; ++c)
                acc[i][c] += xr[i][0] * wr[0][c] + xr[i][1] * wr[1][c]
                           + xr[i][2] * wr[2][c] + xr[i][3] * wr[3][c];
    }

#pragma unroll
    for (int i = 0; i < 4; ++i) {
        int r = brow + tr + i;
        if (r < N_NODES) {
            ushort4 pk;
            pk.x = bf16rne(acc[i][0]); pk.y = bf16rne(acc[i][1]);
            pk.z = bf16rne(acc[i][2]); pk.w = bf16rne(acc[i][3]);
            *(ushort4*)(h2b + r * OUT_CH + tc) = pk;
        }
    }
}

// ---- agg2: per dst node, one wave; halves handle interleaved edges --------
__global__ __launch_bounds__(256) void agg2_kernel(
        const int* __restrict__ rowptr, const int* __restrict__ sortedsrc,
        const float* __restrict__ dis, const unsigned short* __restrict__ h2b,
        const float* __restrict__ b2, float* __restrict__ out) {
    const int lane = threadIdx.x & 63;
    const int c = lane & 31;
    const int half = lane >> 5;
    const int d = blockIdx.x * 4 + (threadIdx.x >> 6);
    if (d >= N_NODES) return;
    const int beg = rowptr[d], end = rowptr[d + 1];
    const float dd = dis[d];
    float a0 = 0.f, a1 = 0.f;
    int j = beg + half;
    for (; j + 2 < end; j += 4) {
        int s0 = sortedsrc[j], s1 = sortedsrc[j + 2];
        a0 += bf16f(h2b[s0 * OUT_CH + c]) * (dis[s0] * dd);
        a1 += bf16f(h2b[s1 * OUT_CH + c]) * (dis[s1] * dd);
    }
    if (j < end) {
        int s0 = sortedsrc[j];
        a0 += bf16f(h2b[s0 * OUT_CH + c]) * (dis[s0] * dd);
    }
    float acc = a0 + a1;
    acc += __shfl_xor(acc, 32, 64);
    if (half == 0) {
        float v = acc + bf16f(h2b[d * OUT_CH + c]) * (dd * dd) + b2[c];
        out[d * OUT_CH + c] = v;
    }
}

extern "C" void kernel_launch(void* const* d_in, const int* in_sizes, int n_in,
                              void* d_out, int out_size, void* d_ws, size_t ws_size,
                              hipStream_t stream) {
    const float* x  = (const float*)d_in[0];
    const float* W1 = (const float*)d_in[1];
    const float* b1 = (const float*)d_in[2];
    const float* W2 = (const float*)d_in[3];
    const float* b2 = (const float*)d_in[4];
    const void*  ei = d_in[5];
    float* out = (float*)d_out;

    char* ws = (char*)d_ws;
    int*   flagp     = (int*)ws;                              // 512 B
    int*   bstart    = (int*)(ws + 512);                      // (NBUCK+1)*4, pad to 1536
    int*   ghistT    = (int*)(ws + 2048);                     // 200704 B
    int*   goff      = (int*)(ws + 2048 + 200704);            // 200704 B
    int*   rowptr    = (int*)(ws + 2048 + 2 * 200704);        // 200704 B
    float* dis       = (float*)(ws + 2048 + 3 * 200704);      // 200704 B
    int*   sortedsrc = (int*)(ws + 2048 + 4 * 200704);                    // 3.2 MB
    unsigned* packed = (unsigned*)((char*)sortedsrc + 3200000);           // 3.2 MB
    unsigned short* h1b = (unsigned short*)((char*)packed + 3200000);     // 6.4 MB
    float* agg1      = (float*)((char*)h1b + (size_t)N_NODES * HID * 2);  // 12.8 MB
    unsigned short* h2b = (unsigned short*)((char*)agg1 + (size_t)N_NODES * HID * 4); // 3.2 MB

    detect_kernel<<<1, 256, 0, stream>>>((const unsigned*)ei, flagp);
    hist_kernel<<<NBLK, 256, 0, stream>>>(ei, flagp, ghistT);
    btot_kernel<<<1, 256, 0, stream>>>(ghistT, bstart);
    offs_kernel<<<NBUCK, 256, 0, stream>>>(bstart, ghistT, goff);
    scatter_kernel<<<NBLK, 256, 0, stream>>>(ei, flagp, goff, packed);
    bucket_kernel<<<NBUCK, 256, 0, stream>>>(bstart, packed, rowptr, dis, sortedsrc);

    gemm1_kernel<<<(N_NODES + 63) / 64, 256, 0, stream>>>(x, W1, h1b);

    agg1_kernel<<<(N_NODES + 3) / 4, 256, 0, stream>>>(rowptr, sortedsrc, dis, h1b, b1, agg1);

    size_t sh2 = (128 * 68 + 64 * 36) * sizeof(float);
    gemm2_kernel<<<(N_NODES + 127) / 128, 256, sh2, stream>>>(agg1, W2, h2b);

    agg2_kernel<<<(N_NODES + 3) / 4, 256, 0, stream>>>(rowptr, sortedsrc, dis, h2b, b2, out);
}

// Round 8
// 112.420 us; speedup vs baseline: 5.4860x; 1.1422x over previous
//
#include <hip/hip_runtime.h>
#include <hip/hip_bf16.h>
#include <cstddef>
#include <cstdint>

#define N_NODES 50000
#define N_EDGES 800000
#define IN_CH 128
#define HID 64
#define OUT_CH 32

#define NBUCK 196    // buckets of 256 dst nodes
#define BCAP 8192    // LDS bucket capacity (mean 4082, sigma ~64)
#define NBLK 256     // partition blocks
#define EPB 3125     // edges per partition block (256*3125 = 800000 exactly)

typedef __attribute__((ext_vector_type(8))) short bf16x8;
typedef __attribute__((ext_vector_type(4))) float f32x4;

// bf16 round-to-nearest-even, bit form
__device__ __forceinline__ unsigned short bf16rne(float f) {
    union { float f; unsigned u; } c; c.f = f;
    unsigned r = c.u + 0x7FFF + ((c.u >> 16) & 1);
    return (unsigned short)(r >> 16);
}
__device__ __forceinline__ float bf16f(unsigned short b) {
    union { unsigned u; float f; } c; c.u = ((unsigned)b) << 16;
    return c.f;
}

// ---------------- edge decode (int32 vs int64 decided at runtime) ----------
__device__ __forceinline__ void load_edge(const void* ei, int flag, int e, int& s, int& d) {
    if (flag) {  // int64 data
        const long long* p = (const long long*)ei;
        s = (int)p[e];
        d = (int)p[e + N_EDGES];
    } else {     // int32 data
        const int* p = (const int*)ei;
        s = p[e];
        d = p[e + N_EDGES];
    }
}
__device__ __forceinline__ int load_dst(const void* ei, int flag, int e) {
    return flag ? (int)((const long long*)ei)[e + N_EDGES]
                : ((const int*)ei)[e + N_EDGES];
}

// flag=1 iff data is int64: odd int32 words (high halves) are all zero.
__global__ __launch_bounds__(256) void detect_kernel(const unsigned* ei, int* flagp) {
    __shared__ unsigned red[256];
    unsigned acc = 0;
    for (int i = threadIdx.x; i < 2048; i += 256) acc |= ei[2 * i + 1];
    red[threadIdx.x] = acc;
    __syncthreads();
    if (threadIdx.x == 0) {
        unsigned o = 0;
        for (int i = 0; i < 256; ++i) o |= red[i];
        *flagp = (o == 0) ? 1 : 0;
    }
}

// ---- pass A: per-block bucket histogram (no global atomics) ---------------
// ghistT layout: [bucket][block]
__global__ __launch_bounds__(256) void hist_kernel(const void* ei, const int* flagp,
                                                   int* __restrict__ ghistT) {
    __shared__ int h[NBUCK];
    const int flag = *flagp;
    const int t = threadIdx.x;
    if (t < NBUCK) h[t] = 0;
    __syncthreads();
    const int base = blockIdx.x * EPB;
    for (int i = t; i < EPB; i += 256)
        atomicAdd(&h[load_dst(ei, flag, base + i) >> 8], 1);
    __syncthreads();
    if (t < NBUCK) ghistT[t * NBLK + blockIdx.x] = h[t];
}

// ---- pass B1: bucket totals + exclusive scan -> bstart[0..NBUCK] ----------
__global__ __launch_bounds__(256) void btot_kernel(const int* __restrict__ ghistT,
                                                   int* __restrict__ bstart) {
    __shared__ int sm[256];
    const int t = threadIdx.x;
    int s = 0;
    if (t < NBUCK) {
        const int* row = ghistT + t * NBLK;
        for (int blk = 0; blk < NBLK; ++blk) s += row[blk];
    }
    sm[t] = s;
    __syncthreads();
    for (int off = 1; off < 256; off <<= 1) {
        int u = (t >= off) ? sm[t - off] : 0;
        __syncthreads();
        sm[t] += u;
        __syncthreads();
    }
    if (t < NBUCK) bstart[t] = sm[t] - s;
    if (t == 255) bstart[NBUCK] = sm[255];
}

// ---- pass B2: per-bucket scan over the 256 block counts -> goff[blk][b] ---
__global__ __launch_bounds__(256) void offs_kernel(const int* __restrict__ bstart,
                                                   const int* __restrict__ ghistT,
                                                   int* __restrict__ goff) {
    __shared__ int sm[256];
    const int b = blockIdx.x;
    const int t = threadIdx.x;
    int v = ghistT[b * NBLK + t];
    sm[t] = v;
    __syncthreads();
    for (int off = 1; off < 256; off <<= 1) {
        int u = (t >= off) ? sm[t - off] : 0;
        __syncthreads();
        sm[t] += u;
        __syncthreads();
    }
    goff[t * NBUCK + b] = bstart[b] + sm[t] - v;  // exclusive prefix
}

// ---- pass C: scatter into disjoint per-(block,bucket) ranges --------------
__global__ __launch_bounds__(256) void scatter_kernel(const void* ei, const int* flagp,
                                                      const int* __restrict__ goff,
                                                      unsigned* __restrict__ packed) {
    __shared__ int lcur[NBUCK];
    const int flag = *flagp;
    const int t = threadIdx.x;
    if (t < NBUCK) lcur[t] = goff[blockIdx.x * NBUCK + t];
    __syncthreads();
    const int base = blockIdx.x * EPB;
    for (int i = t; i < EPB; i += 256) {
        int s, d;
        load_edge(ei, flag, base + i, s, d);
        int b = d >> 8;
        int pos = atomicAdd(&lcur[b], 1);
        packed[pos] = (unsigned)s | ((unsigned)(d & 255) << 16);
    }
}

// ---- pass D: per-bucket LDS sort; also computes rowptr, dis ---------------
__global__ __launch_bounds__(256) void bucket_kernel(const int* __restrict__ bstart,
                                                     const unsigned* __restrict__ packed,
                                                     int* __restrict__ rowptr,
                                                     float* __restrict__ dis,
                                                     int* __restrict__ sortedsrc) {
    __shared__ int cnt[256];
    __shared__ int pref[256];
    __shared__ int lbuf[BCAP];
    const int b = blockIdx.x;
    const int nodebase = b << 8;
    const int rbase = bstart[b];
    const int bsize = bstart[b + 1] - rbase;
    const int t = threadIdx.x;
    const int nb = min(256, N_NODES - nodebase);

    cnt[t] = 0;
    __syncthreads();
    for (int i = t; i < bsize; i += 256)
        atomicAdd(&cnt[packed[rbase + i] >> 16], 1);
    __syncthreads();
    const int deg = cnt[t];
    pref[t] = deg;
    __syncthreads();
    for (int off = 1; off < 256; off <<= 1) {
        int u = (t >= off) ? pref[t - off] : 0;
        __syncthreads();
        pref[t] += u;
        __syncthreads();
    }
    const int excl = pref[t] - deg;
    if (t < nb) {
        rowptr[nodebase + t] = rbase + excl;
        dis[nodebase + t] = rsqrtf((float)deg + 1.0f);
    }
    if (b == NBUCK - 1 && t == 0) rowptr[N_NODES] = rbase + bsize;
    __syncthreads();
    cnt[t] = excl;  // reuse as cursor
    __syncthreads();
    if (bsize <= BCAP) {
        for (int i = t; i < bsize; i += 256) {
            unsigned p = packed[rbase + i];
            int pos = atomicAdd(&cnt[p >> 16], 1);
            lbuf[pos] = (int)(p & 0xFFFFu);
        }
        __syncthreads();
        for (int i = t; i < bsize; i += 256)
            sortedsrc[rbase + i] = lbuf[i];
    } else {
        // fallback: direct global scatter (pathological skew only)
        for (int i = t; i < bsize; i += 256) {
            unsigned p = packed[rbase + i];
            int pos = atomicAdd(&cnt[p >> 16], 1);
            sortedsrc[rbase + pos] = (int)(p & 0xFFFFu);
        }
    }
}

// --------------- GEMM1 (MFMA bf16): h1b = bf16(x @ W1) ---------------------
// block: 64 rows x 64 cols, K=128; 4 waves, each wave 16 rows x 64 cols.
__global__ __launch_bounds__(256) void gemm1_kernel(
        const float* __restrict__ x, const float* __restrict__ W1,
        unsigned short* __restrict__ h1b) {
    __shared__ unsigned short xa[64][136];  // x tile, bf16, +8 pad
    __shared__ unsigned short wb[64][136];  // W1 transposed [n][k], bf16
    const int t = threadIdx.x;
    const int w = t >> 6;
    const int l = t & 63;
    const int brow = blockIdx.x * 64;

    // stage x (64x128 f32 -> bf16)
    for (int f = t; f < 64 * 32; f += 256) {
        int r = f >> 5, c = (f & 31) << 2;
        int gr = brow + r;
        float4 v = (gr < N_NODES) ? *(const float4*)(x + gr * IN_CH + c)
                                  : make_float4(0.f, 0.f, 0.f, 0.f);
        xa[r][c + 0] = bf16rne(v.x); xa[r][c + 1] = bf16rne(v.y);
        xa[r][c + 2] = bf16rne(v.z); xa[r][c + 3] = bf16rne(v.w);
    }
    // stage W1 (128x64 f32) transposed -> wb[n][k] bf16
    for (int f = t; f < 128 * 16; f += 256) {
        int k = f >> 4, n = (f & 15) << 2;
        float4 v = *(const float4*)(W1 + k * HID + n);
        wb[n + 0][k] = bf16rne(v.x); wb[n + 1][k] = bf16rne(v.y);
        wb[n + 2][k] = bf16rne(v.z); wb[n + 3][k] = bf16rne(v.w);
    }
    __syncthreads();

    const int fr = l & 15;          // A row / B col within 16-tile
    const int fk = (l >> 4) << 3;   // k sub-offset (0,8,16,24)
    f32x4 acc[4] = {{0.f,0.f,0.f,0.f},{0.f,0.f,0.f,0.f},{0.f,0.f,0.f,0.f},{0.f,0.f,0.f,0.f}};
#pragma unroll
    for (int kb = 0; kb < 4; ++kb) {
        const int k = kb * 32 + fk;
        bf16x8 a = *(const bf16x8*)&xa[w * 16 + fr][k];
#pragma unroll
        for (int n = 0; n < 4; ++n) {
            bf16x8 bfr = *(const bf16x8*)&wb[n * 16 + fr][k];
            acc[n] = __builtin_amdgcn_mfma_f32_16x16x32_bf16(a, bfr, acc[n], 0, 0, 0);
        }
    }
    // C/D: col = n*16 + (l&15), row = brow + w*16 + (l>>4)*4 + i
    const int rb = brow + w * 16 + ((l >> 4) << 2);
#pragma unroll
    for (int n = 0; n < 4; ++n) {
#pragma unroll
        for (int i = 0; i < 4; ++i) {
            int r = rb + i;
            if (r < N_NODES) h1b[r * HID + n * 16 + fr] = bf16rne(acc[n][i]);
        }
    }
}

// ---- agg1: wave per dst; 4 groups x 16 lanes, ushort4 (8B) gathers --------
// agg1b[d][c] = bf16(relu( sum_j h1[src_j][c]*norm_j + h1[d][c]*dd^2 + b1[c] ))
__global__ __launch_bounds__(256) void agg1_kernel(
        const int* __restrict__ rowptr, const int* __restrict__ sortedsrc,
        const float* __restrict__ dis, const unsigned short* __restrict__ h1b,
        const float* __restrict__ b1, unsigned short* __restrict__ agg1b) {
    const int l = threadIdx.x & 63;
    const int g = l >> 4;    // edge group 0-3
    const int cl = l & 15;   // channel quad -> channels 4cl..4cl+3
    const int d = blockIdx.x * 4 + (threadIdx.x >> 6);
    if (d >= N_NODES) return;
    const int beg = rowptr[d], end = rowptr[d + 1];
    const float dd = dis[d];
    float a0 = 0.f, a1 = 0.f, a2 = 0.f, a3 = 0.f;
    for (int j = beg + g; j < end; j += 4) {
        int s = sortedsrc[j];
        float n = dis[s] * dd;
        ushort4 h = *(const ushort4*)(h1b + s * HID + 4 * cl);
        a0 += bf16f(h.x) * n; a1 += bf16f(h.y) * n;
        a2 += bf16f(h.z) * n; a3 += bf16f(h.w) * n;
    }
    // reduce across the 4 edge-groups (lane bits 4,5)
    a0 += __shfl_xor(a0, 16, 64); a1 += __shfl_xor(a1, 16, 64);
    a2 += __shfl_xor(a2, 16, 64); a3 += __shfl_xor(a3, 16, 64);
    a0 += __shfl_xor(a0, 32, 64); a1 += __shfl_xor(a1, 32, 64);
    a2 += __shfl_xor(a2, 32, 64); a3 += __shfl_xor(a3, 32, 64);
    if (g == 0) {
        ushort4 hs = *(const ushort4*)(h1b + d * HID + 4 * cl);
        float4 bv = *(const float4*)(b1 + 4 * cl);
        float d2 = dd * dd;
        a0 = fmaxf(a0 + bf16f(hs.x) * d2 + bv.x, 0.f);
        a1 = fmaxf(a1 + bf16f(hs.y) * d2 + bv.y, 0.f);
        a2 = fmaxf(a2 + bf16f(hs.z) * d2 + bv.z, 0.f);
        a3 = fmaxf(a3 + bf16f(hs.w) * d2 + bv.w, 0.f);
        ushort4 o;
        o.x = bf16rne(a0); o.y = bf16rne(a1); o.z = bf16rne(a2); o.w = bf16rne(a3);
        *(ushort4*)(agg1b + d * HID + 4 * cl) = o;
    }
}

// --------------- GEMM2 (MFMA bf16): h2b = bf16(agg1b @ W2) -----------------
// block: 64 rows x 32 cols, K=64; 4 waves, each wave 16 rows x 32 cols.
__global__ __launch_bounds__(256) void gemm2_kernel(
        const unsigned short* __restrict__ agg1b, const float* __restrict__ W2,
        unsigned short* __restrict__ h2b) {
    __shared__ unsigned short xa[64][72];   // agg1b tile (64x64), +8 pad
    __shared__ unsigned short wb[32][72];   // W2 transposed [n][k]
    const int t = threadIdx.x;
    const int w = t >> 6;
    const int l = t & 63;
    const int brow = blockIdx.x * 64;

    // stage agg1b tile (bf16 copy)
    for (int f = t; f < 64 * 16; f += 256) {
        int r = f >> 4, c = (f & 15) << 2;
        int gr = brow + r;
        ushort4 v = make_ushort4(0, 0, 0, 0);
        if (gr < N_NODES) v = *(const ushort4*)(agg1b + gr * HID + c);
        *(ushort4*)&xa[r][c] = v;
    }
    // stage W2 (64x32 f32) transposed -> wb[n][k] bf16
    for (int f = t; f < 64 * 8; f += 256) {
        int k = f >> 3, n = (f & 7) << 2;
        float4 v = *(const float4*)(W2 + k * OUT_CH + n);
        wb[n + 0][k] = bf16rne(v.x); wb[n + 1][k] = bf16rne(v.y);
        wb[n + 2][k] = bf16rne(v.z); wb[n + 3][k] = bf16rne(v.w);
    }
    __syncthreads();

    const int fr = l & 15;
    const int fk = (l >> 4) << 3;
    f32x4 acc[2] = {{0.f,0.f,0.f,0.f},{0.f,0.f,0.f,0.f}};
#pragma unroll
    for (int kb = 0; kb < 2; ++kb) {
        const int k = kb * 32 + fk;
        bf16x8 a = *(const bf16x8*)&xa[w * 16 + fr][k];
#pragma unroll
        for (int n = 0; n < 2; ++n) {
            bf16x8 bfr = *(const bf16x8*)&wb[n * 16 + fr][k];
            acc[n] = __builtin_amdgcn_mfma_f32_16x16x32_bf16(a, bfr, acc[n], 0, 0, 0);
        }
    }
    const int rb = brow + w * 16 + ((l >> 4) << 2);
#pragma unroll
    for (int n = 0; n < 2; ++n) {
#pragma unroll
        for (int i = 0; i < 4; ++i) {
            int r = rb + i;
            if (r < N_NODES) h2b[r * OUT_CH + n * 16 + fr] = bf16rne(acc[n][i]);
        }
    }
}

// ---- agg2: wave per dst; 8 groups x 8 lanes, ushort4 (8B) gathers ---------
// out[d][c] = sum_j h2[src_j][c]*norm_j + h2[d][c]*dd^2 + b2[c]
__global__ __launch_bounds__(256) void agg2_kernel(
        const int* __restrict__ rowptr, const int* __restrict__ sortedsrc,
        const float* __restrict__ dis, const unsigned short* __restrict__ h2b,
        const float* __restrict__ b2, float* __restrict__ out) {
    const int l = threadIdx.x & 63;
    const int g = l >> 3;    // edge group 0-7
    const int cl = l & 7;    // channel quad -> channels 4cl..4cl+3
    const int d = blockIdx.x * 4 + (threadIdx.x >> 6);
    if (d >= N_NODES) return;
    const int beg = rowptr[d], end = rowptr[d + 1];
    const float dd = dis[d];
    float a0 = 0.f, a1 = 0.f, a2 = 0.f, a3 = 0.f;
    for (int j = beg + g; j < end; j += 8) {
        int s = sortedsrc[j];
        float n = dis[s] * dd;
        ushort4 h = *(const ushort4*)(h2b + s * OUT_CH + 4 * cl);
        a0 += bf16f(h.x) * n; a1 += bf16f(h.y) * n;
        a2 += bf16f(h.z) * n; a3 += bf16f(h.w) * n;
    }
    // reduce across the 8 edge-groups (lane bits 3,4,5)
    a0 += __shfl_xor(a0, 8, 64);  a1 += __shfl_xor(a1, 8, 64);
    a2 += __shfl_xor(a2, 8, 64);  a3 += __shfl_xor(a3, 8, 64);
    a0 += __shfl_xor(a0, 16, 64); a1 += __shfl_xor(a1, 16, 64);
    a2 += __shfl_xor(a2, 16, 64); a3 += __shfl_xor(a3, 16, 64);
    a0 += __shfl_xor(a0, 32, 64); a1 += __shfl_xor(a1, 32, 64);
    a2 += __shfl_xor(a2, 32, 64); a3 += __shfl_xor(a3, 32, 64);
    if (g == 0) {
        ushort4 hs = *(const ushort4*)(h2b + d * OUT_CH + 4 * cl);
        float4 bv = *(const float4*)(b2 + 4 * cl);
        float d2 = dd * dd;
        float4 o;
        o.x = a0 + bf16f(hs.x) * d2 + bv.x;
        o.y = a1 + bf16f(hs.y) * d2 + bv.y;
        o.z = a2 + bf16f(hs.z) * d2 + bv.z;
        o.w = a3 + bf16f(hs.w) * d2 + bv.w;
        *(float4*)(out + d * OUT_CH + 4 * cl) = o;
    }
}

extern "C" void kernel_launch(void* const* d_in, const int* in_sizes, int n_in,
                              void* d_out, int out_size, void* d_ws, size_t ws_size,
                              hipStream_t stream) {
    const float* x  = (const float*)d_in[0];
    const float* W1 = (const float*)d_in[1];
    const float* b1 = (const float*)d_in[2];
    const float* W2 = (const float*)d_in[3];
    const float* b2 = (const float*)d_in[4];
    const void*  ei = d_in[5];
    float* out = (float*)d_out;

    char* ws = (char*)d_ws;
    int*   flagp     = (int*)ws;                              // 512 B
    int*   bstart    = (int*)(ws + 512);                      // (NBUCK+1)*4
    int*   ghistT    = (int*)(ws + 2048);                     // 200704 B
    int*   goff      = (int*)(ws + 2048 + 200704);            // 200704 B
    int*   rowptr    = (int*)(ws + 2048 + 2 * 200704);        // 200704 B
    float* dis       = (float*)(ws + 2048 + 3 * 200704);      // 200704 B
    int*   sortedsrc = (int*)(ws + 2048 + 4 * 200704);                    // 3.2 MB
    unsigned* packed = (unsigned*)((char*)sortedsrc + 3200000);           // 3.2 MB
    unsigned short* h1b = (unsigned short*)((char*)packed + 3200000);     // 6.4 MB
    unsigned short* agg1b = (unsigned short*)((char*)h1b + (size_t)N_NODES * HID * 2);  // 6.4 MB
    unsigned short* h2b = (unsigned short*)((char*)agg1b + (size_t)N_NODES * HID * 2);  // 3.2 MB

    detect_kernel<<<1, 256, 0, stream>>>((const unsigned*)ei, flagp);
    hist_kernel<<<NBLK, 256, 0, stream>>>(ei, flagp, ghistT);
    btot_kernel<<<1, 256, 0, stream>>>(ghistT, bstart);
    offs_kernel<<<NBUCK, 256, 0, stream>>>(bstart, ghistT, goff);
    scatter_kernel<<<NBLK, 256, 0, stream>>>(ei, flagp, goff, packed);
    bucket_kernel<<<NBUCK, 256, 0, stream>>>(bstart, packed, rowptr, dis, sortedsrc);

    gemm1_kernel<<<(N_NODES + 63) / 64, 256, 0, stream>>>(x, W1, h1b);

    agg1_kernel<<<(N_NODES + 3) / 4, 256, 0, stream>>>(rowptr, sortedsrc, dis, h1b, b1, agg1b);

    gemm2_kernel<<<(N_NODES + 63) / 64, 256, 0, stream>>>(agg1b, W2, h2b);

    agg2_kernel<<<(N_NODES + 3) / 4, 256, 0, stream>>>(rowptr, sortedsrc, dis, h2b, b2, out);
}